// Round 6
// baseline (235.850 us; speedup 1.0000x reference)
//
#include <hip/hip_runtime.h>

typedef unsigned short u16;
typedef __attribute__((ext_vector_type(8))) short short8;   // 8 bf16 = 4 VGPRs
typedef __attribute__((ext_vector_type(4))) float floatx4;

#define MFMA16(a, b, c) __builtin_amdgcn_mfma_f32_16x16x32_bf16(a, b, c, 0, 0, 0)

__device__ inline u16 bf16rn(float x) {
    unsigned u = __float_as_uint(x);
    u += 0x7fffu + ((u >> 16) & 1u);
    return (u16)(u >> 16);
}
__device__ inline float bf16tof(u16 h) { return __uint_as_float(((unsigned)h) << 16); }
__device__ inline short8 ld8(const u16* p) { return *(const short8*)p; }

// ---------------------------------------------------------------------------
// Consolidated precompute: E transpose (blk<32), rel K rows (blk 32..63),
// conv14 weight transpose w2[g][ic][oc*9+kk] (blk 64..71).
__global__ __launch_bounds__(256) void k_ecvt2(const float* __restrict__ E,
                                               const float* __restrict__ rel,
                                               const float* __restrict__ w,
                                               u16* __restrict__ EhT,
                                               u16* __restrict__ ElT,
                                               u16* __restrict__ Kh,
                                               u16* __restrict__ Kl,
                                               u16* __restrict__ KhT,
                                               u16* __restrict__ KlT,
                                               float* __restrict__ w2) {
    int blk = blockIdx.x, tid = threadIdx.x;
    if (blk < 32) {                       // E transpose + hi/lo
        __shared__ float ep[196 * 65];
        int m = blk;
        const float* eb = E + (size_t)m * 12544;
        for (int t = tid; t < 12544; t += 256) {
            int p = t >> 6, h = t & 63;
            ep[p * 65 + h] = eb[t];
        }
        __syncthreads();
        for (int t = tid; t < 64 * 224; t += 256) {
            int h = t / 224, p = t % 224;
            float v = (p < 196) ? ep[p * 65 + h] : 0.f;
            u16 hi = bf16rn(v);
            u16 lo = bf16rn(v - bf16tof(hi));
            EhT[(size_t)m * 14336 + t] = hi;
            ElT[(size_t)m * 14336 + t] = lo;
        }
    } else if (blk < 64) {                // rel rows -> K arrays (i 2048..2111)
        int b = blk - 32;
        size_t bK = (size_t)b * 2112;
        size_t bT = (size_t)b * 33792;
#pragma unroll
        for (int k = 0; k < 4; ++k) {
            int idx = tid + k * 256;      // [0,1024)
            int row = idx >> 4, e = idx & 15;
            int i = 2048 + row;
            float v = (row < 49) ? rel[e * 49 + row] : 0.f;
            u16 h = bf16rn(v);
            u16 l = bf16rn(v - bf16tof(h));
            Kh[(bK + i) * 16 + e] = h;
            Kl[(bK + i) * 16 + e] = l;
            KhT[bT + (size_t)e * 2112 + i] = h;
            KlT[bT + (size_t)e * 2112 + i] = l;
        }
    } else {                              // conv14 weight transpose, 4 g per block
        int g0 = (blk - 64) * 4;
        for (int t = tid; t < 4 * 2304; t += 256) {
            int g = g0 + t / 2304, r = t % 2304;
            int oc = r / 144, rr = r % 144;
            w2[(size_t)g * 2304 + (rr / 9) * 144 + oc * 9 + (rr % 9)] =
                w[(size_t)g * 2304 + r];
        }
    }
}

// ---------------------------------------------------------------------------
// Grouped 3x3 conv 14x14, oc-split x2, transposed weights.
__global__ __launch_bounds__(256) void k_conv14(const float* __restrict__ pose,
                                                const float* __restrict__ w2,
                                                float* __restrict__ out) {
    int blk = blockIdx.x;          // (b*32+g)*2 + oh
    int oh = blk & 1, bg = blk >> 1;
    int tid = threadIdx.x;
    __shared__ float patch[16 * 256];
#pragma unroll
    for (int k = 0; k < 16; ++k) patch[k * 256 + tid] = 0.f;
    __syncthreads();
    const float* pin = pose + (size_t)bg * 3136;
    for (int t = tid; t < 3136; t += 256) {
        int p = t >> 4, ic = t & 15;
        int y = p / 14, x = p % 14;
        patch[ic * 256 + (y + 1) * 16 + (x + 1)] = pin[t];
    }
    __syncthreads();
    int g = bg & 31;
    const float* wg = w2 + (size_t)g * 2304 + oh * 72;
    float* po = out + (size_t)bg * 3136 + oh * 8 * 196;
    if (tid < 196) {
        int y = tid / 14, x = tid % 14;
        int base = (y + 1) * 16 + (x + 1);
        float acc[8];
#pragma unroll
        for (int oc = 0; oc < 8; ++oc) acc[oc] = 0.f;
        for (int ic = 0; ic < 16; ++ic) {
            const float* pr = patch + ic * 256 + base;
            float win[9];
#pragma unroll
            for (int ky = 0; ky < 3; ++ky)
#pragma unroll
                for (int kx = 0; kx < 3; ++kx)
                    win[ky * 3 + kx] = pr[(ky - 1) * 16 + (kx - 1)];
            const float* wi = wg + ic * 144;
#pragma unroll
            for (int oc = 0; oc < 8; ++oc)
#pragma unroll
                for (int kk = 0; kk < 9; ++kk)
                    acc[oc] += win[kk] * wi[oc * 9 + kk];
        }
#pragma unroll
        for (int oc = 0; oc < 8; ++oc) po[oc * 196 + tid] = acc[oc];
    }
}

// ---------------------------------------------------------------------------
// Q-path conv 7x7 (permuted pose input) fused with Q bf16 hi/lo conversion.
// 128 threads: wave0 -> oc 0..7, wave1 -> oc 8..15.
__global__ __launch_bounds__(128) void k_conv7q(const float* __restrict__ pose,
                                                const float* __restrict__ w,
                                                u16* __restrict__ Qp) {
    int bg = blockIdx.x;           // b*32+g
    int tid = threadIdx.x;
    __shared__ float patch[16 * 144];
    __shared__ float cvout[784];
    for (int t = tid; t < 16 * 144; t += 128) patch[t] = 0.f;
    __syncthreads();
    const float* pin = pose + (size_t)bg * 784;
    for (int t = tid; t < 784; t += 128) {
        int p = t >> 4, ic = t & 15;
        int y = p / 7, x = p % 7;
        patch[ic * 144 + (y + 1) * 16 + (x + 1)] = pin[t];
    }
    __syncthreads();
    int g = bg & 31;
    int oh = tid >> 6, lt = tid & 63;
    const float* wg = w + (size_t)g * 2304 + (size_t)oh * 8 * 144;
    if (lt < 49) {
        int y = lt / 7, x = lt % 7;
        int base = (y + 1) * 16 + (x + 1);
        float acc[8];
#pragma unroll
        for (int oc = 0; oc < 8; ++oc) acc[oc] = 0.f;
        for (int ic = 0; ic < 16; ++ic) {
            const float* pr = patch + ic * 144 + base;
            float win[9];
#pragma unroll
            for (int ky = 0; ky < 3; ++ky)
#pragma unroll
                for (int kx = 0; kx < 3; ++kx)
                    win[ky * 3 + kx] = pr[(ky - 1) * 16 + (kx - 1)];
            const float* wi = wg + ic * 9;
#pragma unroll
            for (int oc = 0; oc < 8; ++oc)
#pragma unroll
                for (int kk = 0; kk < 9; ++kk)
                    acc[oc] += win[kk] * wi[oc * 144 + kk];
        }
#pragma unroll
        for (int oc = 0; oc < 8; ++oc) cvout[(oh * 8 + oc) * 49 + lt] = acc[oc];
    }
    __syncthreads();
    if (tid < 49) {                       // convert row j = bg*49+tid
        float v[16];
#pragma unroll
        for (int k = 0; k < 16; ++k) v[k] = cvout[tid * 16 + k];
        unsigned hw[8], lw[8];
#pragma unroll
        for (int t = 0; t < 8; ++t) {
            float x0 = v[2*t] * 0.25f, x1 = v[2*t+1] * 0.25f;
            u16 h0 = bf16rn(x0), h1 = bf16rn(x1);
            u16 l0 = bf16rn(x0 - bf16tof(h0)), l1 = bf16rn(x1 - bf16tof(h1));
            hw[t] = (unsigned)h0 | ((unsigned)h1 << 16);
            lw[t] = (unsigned)l0 | ((unsigned)l1 << 16);
        }
        size_t j = (size_t)bg * 49 + tid;
        uint4* r4 = (uint4*)(Qp + j * 32);
        r4[0] = make_uint4(hw[0], hw[1], hw[2], hw[3]);
        r4[1] = make_uint4(hw[4], hw[5], hw[6], hw[7]);
        r4[2] = make_uint4(lw[0], lw[1], lw[2], lw[3]);
        r4[3] = make_uint4(lw[4], lw[5], lw[6], lw[7]);
    }
}

// ---------------------------------------------------------------------------
// MFMA key projection (unchanged).
__global__ __launch_bounds__(256) void k_kproj2(const float* __restrict__ cpconv,
                                                const u16* __restrict__ EhT,
                                                const u16* __restrict__ ElT,
                                                u16* __restrict__ Kh,
                                                u16* __restrict__ Kl,
                                                u16* __restrict__ KhT,
                                                u16* __restrict__ KlT) {
    int blk = blockIdx.x;           // b*32 + m
    int b = blk >> 5, m = blk & 31;
    int wave = threadIdx.x >> 6, lane = threadIdx.x & 63;
    int ht = wave;
    int n = lane & 15, quad = lane >> 4;

    const float* arow = cpconv + ((size_t)b * 512 + (size_t)n * 32 + m) * 196;
    const u16* bhrow = EhT + ((size_t)m * 64 + ht * 16 + n) * 224;
    const u16* blrow = ElT + ((size_t)m * 64 + ht * 16 + n) * 224;

    floatx4 c = {0.f, 0.f, 0.f, 0.f};
#pragma unroll
    for (int pc = 0; pc < 7; ++pc) {
        int p0 = pc * 32 + quad * 8;
        float av[8];
        if (p0 <= 188) {
            float4 x = *(const float4*)(arow + p0);
            float4 y = *(const float4*)(arow + p0 + 4);
            av[0]=x.x; av[1]=x.y; av[2]=x.z; av[3]=x.w;
            av[4]=y.x; av[5]=y.y; av[6]=y.z; av[7]=y.w;
        } else {
#pragma unroll
            for (int k2 = 0; k2 < 8; ++k2) av[k2] = (p0 + k2 < 196) ? arow[p0 + k2] : 0.f;
        }
        short8 ah, al;
#pragma unroll
        for (int k2 = 0; k2 < 8; ++k2) {
            u16 h = bf16rn(av[k2]);
            ah[k2] = (short)h;
            al[k2] = (short)bf16rn(av[k2] - bf16tof(h));
        }
        short8 bh = ld8(bhrow + pc * 32 + quad * 8);
        short8 bl = ld8(blrow + pc * 32 + quad * 8);
        c = MFMA16(ah, bh, c);
        c = MFMA16(ah, bl, c);
        c = MFMA16(al, bh, c);
    }
    int i = m * 64 + ht * 16 + n;
    size_t bK = (size_t)b * 2112;
    size_t bT = (size_t)b * 33792;
    u16 h[4], l[4];
#pragma unroll
    for (int r = 0; r < 4; ++r) {
        h[r] = bf16rn(c[r]);
        l[r] = bf16rn(c[r] - bf16tof(h[r]));
    }
    *(uint2*)(Kh + (bK + i) * 16 + quad * 4) =
        make_uint2((unsigned)h[0] | ((unsigned)h[1] << 16), (unsigned)h[2] | ((unsigned)h[3] << 16));
    *(uint2*)(Kl + (bK + i) * 16 + quad * 4) =
        make_uint2((unsigned)l[0] | ((unsigned)l[1] << 16), (unsigned)l[2] | ((unsigned)l[3] << 16));
#pragma unroll
    for (int r = 0; r < 4; ++r) {
        KhT[bT + (size_t)(quad * 4 + r) * 2112 + i] = h[r];
        KlT[bT + (size_t)(quad * 4 + r) * 2112 + i] = l[r];
    }
}

// ---------------------------------------------------------------------------
// Column denominators (unchanged structure).
__global__ __launch_bounds__(256) void k_stats4(const u16* __restrict__ Qp,
                                                const u16* __restrict__ Kh,
                                                const u16* __restrict__ Kl,
                                                float* __restrict__ dpart) {
    int blk = blockIdx.x;                   // b*34 + jh*17 + tb
    int b = blk / 34; int rem = blk % 34; int jh = rem / 17; int tb = rem % 17;
    int wave = threadIdx.x >> 6, lane = threadIdx.x & 63;
    int it2 = tb * 4 + wave;
    if (it2 >= 66) return;
    int ibase = it2 * 32;
    int n = lane & 15, quad = lane >> 4;
    size_t bK = (size_t)b * 2112;
    const u16* kb = Kh + (bK + ibase + n) * 16 + (quad & 1) * 8;
    const u16* lb = Kl + (bK + ibase + n) * 16 + (quad & 1) * 8;
    short8 bh0 = ld8(kb), bh1 = ld8(kb + 256);
    short8 bl0 = ld8(lb), bl1 = ld8(lb + 256);
    const u16* qb = Qp + (size_t)b * 50176 + (size_t)jh * 49 * 512 + n * 32 + quad * 8;
    floatx4 d0 = {0.f,0.f,0.f,0.f}, d1 = {0.f,0.f,0.f,0.f};
    short8 a0 = ld8(qb), a1 = ld8(qb + 512);
    for (int c = 0; c < 49; ++c) {
        short8 a2 = (c + 2 < 49) ? ld8(qb + (size_t)(c + 2) * 512) : a0;
        floatx4 s0 = {0.f,0.f,0.f,0.f}, s1 = {0.f,0.f,0.f,0.f};
        s0 = MFMA16(a0, bh0, s0);
        s0 = MFMA16(a0, bl0, s0);
        s1 = MFMA16(a0, bh1, s1);
        s1 = MFMA16(a0, bl1, s1);
        d0.x += __expf(s0.x); d0.y += __expf(s0.y);
        d0.z += __expf(s0.z); d0.w += __expf(s0.w);
        d1.x += __expf(s1.x); d1.y += __expf(s1.y);
        d1.z += __expf(s1.z); d1.w += __expf(s1.w);
        a0 = a1; a1 = a2;
    }
    float t0 = d0.x + d0.y + d0.z + d0.w;
    float t1 = d1.x + d1.y + d1.z + d1.w;
    t0 += __shfl_xor(t0, 16); t0 += __shfl_xor(t0, 32);
    t1 += __shfl_xor(t1, 16); t1 += __shfl_xor(t1, 32);
    if (quad == 0) {
        dpart[(size_t)jh * 67584 + bK + ibase + n]      = t0;
        dpart[(size_t)jh * 67584 + bK + ibase + 16 + n] = t1;
    }
}

// ---------------------------------------------------------------------------
// Scale KhT/KlT rows by 1/D[i] (fold softmax denominator into K).
__global__ __launch_bounds__(256) void k_kscale(const float* __restrict__ dpart,
                                                u16* __restrict__ KhT,
                                                u16* __restrict__ KlT) {
    int blk = blockIdx.x;          // b*4 + q
    int b = blk >> 2, q = blk & 3;
    int tid = threadIdx.x;
    size_t bT = (size_t)b * 33792;
    const float* d0 = dpart + (size_t)b * 2112;
    const float* d1 = dpart + 67584 + (size_t)b * 2112;
    for (int t = tid; t < 1056; t += 256) {
        int v = q * 1056 + t;               // vector of 8 u16
        int e = v / 264, i8 = (v % 264) * 8;
        size_t off = bT + (size_t)e * 2112 + i8;
        uint4 hv = *(uint4*)(KhT + off);
        uint4 lv = *(uint4*)(KlT + off);
        float4 da = *(const float4*)(d0 + i8), db = *(const float4*)(d0 + i8 + 4);
        float4 ea = *(const float4*)(d1 + i8), eb = *(const float4*)(d1 + i8 + 4);
        float rl[8] = {1.f/(da.x+ea.x), 1.f/(da.y+ea.y), 1.f/(da.z+ea.z), 1.f/(da.w+ea.w),
                       1.f/(db.x+eb.x), 1.f/(db.y+eb.y), 1.f/(db.z+eb.z), 1.f/(db.w+eb.w)};
        unsigned hu[4] = {hv.x, hv.y, hv.z, hv.w};
        unsigned lu[4] = {lv.x, lv.y, lv.z, lv.w};
        unsigned ho[4], lo4[4];
#pragma unroll
        for (int k = 0; k < 4; ++k) {
            u16 h0 = (u16)hu[k], h1 = (u16)(hu[k] >> 16);
            u16 l0 = (u16)lu[k], l1 = (u16)(lu[k] >> 16);
            float v0 = (bf16tof(h0) + bf16tof(l0)) * rl[2*k];
            float v1 = (bf16tof(h1) + bf16tof(l1)) * rl[2*k+1];
            u16 nh0 = bf16rn(v0), nh1 = bf16rn(v1);
            u16 nl0 = bf16rn(v0 - bf16tof(nh0)), nl1 = bf16rn(v1 - bf16tof(nh1));
            ho[k]  = (unsigned)nh0 | ((unsigned)nh1 << 16);
            lo4[k] = (unsigned)nl0 | ((unsigned)nl1 << 16);
        }
        *(uint4*)(KhT + off) = make_uint4(ho[0], ho[1], ho[2], ho[3]);
        *(uint4*)(KlT + off) = make_uint4(lo4[0], lo4[1], lo4[2], lo4[3]);
    }
}

// ---------------------------------------------------------------------------
// PV: software-pipelined W transpose (PV consumes W of previous chunk),
// denominator pre-folded into KT, i-split x3.
__global__ __launch_bounds__(256) void k_pv6(const u16* __restrict__ Qp,
                                             const u16* __restrict__ Kh,
                                             const u16* __restrict__ Kl,
                                             const u16* __restrict__ KhT,
                                             const u16* __restrict__ KlT,
                                             float* __restrict__ opart) {
    __shared__ __align__(16) u16 sH[2][32][16];       // Kh rows
    __shared__ __align__(16) u16 sL[2][32][16];       // Kl rows
    __shared__ __align__(16) u16 tH[2][16][32];       // scaled KhT
    __shared__ __align__(16) u16 tL[2][16][32];       // scaled KlT
    __shared__ __align__(16) u16 w16[4][2][16][40];   // per-wave W dbuf

    int blk = blockIdx.x;                  // b*75 + jtb*3 + ih
    int b = blk / 75; int rem = blk % 75; int jtb = rem / 3; int ih = rem % 3;
    int tid = threadIdx.x, wave = tid >> 6, lane = tid & 63;
    int n = lane & 15, quad = lane >> 4, qh = quad & 1;
    int jt = jtb * 4 + wave;
    int jtc = jt < 98 ? jt : 97;
    int i0 = ih * 704;                     // 22 chunks of 32
    size_t bK = (size_t)b * 2112;
    size_t bT = (size_t)b * 33792;

    short8 aq = ld8(Qp + ((size_t)b * 1568 + (size_t)jtc * 16 + n) * 32 + quad * 8);

    int role = wave, L = lane;
    uint4 sreg;
    auto ldchunk = [&](int c) {
        int i0c = i0 + c * 32;
        if (role == 0)      sreg = *(const uint4*)(Kh  + (bK + i0c + (L >> 1)) * 16 + (L & 1) * 8);
        else if (role == 1) sreg = *(const uint4*)(Kl  + (bK + i0c + (L >> 1)) * 16 + (L & 1) * 8);
        else if (role == 2) sreg = *(const uint4*)(KhT + bT + (size_t)(L >> 2) * 2112 + i0c + (L & 3) * 8);
        else                sreg = *(const uint4*)(KlT + bT + (size_t)(L >> 2) * 2112 + i0c + (L & 3) * 8);
    };
    auto stchunk = [&](int bf) {
        if (role == 0)      *(uint4*)(&sH[bf][L >> 1][(L & 1) * 8]) = sreg;
        else if (role == 1) *(uint4*)(&sL[bf][L >> 1][(L & 1) * 8]) = sreg;
        else if (role == 2) *(uint4*)(&tH[bf][L >> 2][(L & 3) * 8]) = sreg;
        else                *(uint4*)(&tL[bf][L >> 2][(L & 3) * 8]) = sreg;
    };

    floatx4 o = {0.f, 0.f, 0.f, 0.f};
    short8 thp = {}, tlp = {};

    ldchunk(0); stchunk(0); ldchunk(1);
    __syncthreads();
    for (int c = 0; c < 22; ++c) {
        int cb = c & 1;
        short8 th  = ld8(&tH[cb][n][quad * 8]);
        short8 tl  = ld8(&tL[cb][n][quad * 8]);
        short8 sh0 = ld8(&sH[cb][n][qh * 8]);
        short8 sh1 = ld8(&sH[cb][16 + n][qh * 8]);
        short8 sl0 = ld8(&sL[cb][n][qh * 8]);
        short8 sl1 = ld8(&sL[cb][16 + n][qh * 8]);
        short8 aw = {};
        if (c > 0) aw = ld8(&w16[wave][1 - cb][n][quad * 8]);   // W of chunk c-1
        floatx4 s0 = {0.f,0.f,0.f,0.f};
        s0 = MFMA16(aq, sh0, s0);
        s0 = MFMA16(aq, sl0, s0);
        floatx4 s1 = {0.f,0.f,0.f,0.f};
        s1 = MFMA16(aq, sh1, s1);
        s1 = MFMA16(aq, sl1, s1);
        if (c > 0) {                                            // PV for chunk c-1
            o = MFMA16(aw, thp, o);
            o = MFMA16(aw, tlp, o);
        }
#pragma unroll
        for (int r = 0; r < 4; ++r) {
            float w0 = __expf(s0[r]);
            float w1 = __expf(s1[r]);
            w16[wave][cb][quad * 4 + r][n]      = (u16)(__float_as_uint(w0) >> 16);
            w16[wave][cb][quad * 4 + r][16 + n] = (u16)(__float_as_uint(w1) >> 16);
        }
        thp = th; tlp = tl;
        if (c + 1 < 22) stchunk((c + 1) & 1);
        if (c + 2 < 22) ldchunk(c + 2);
        __syncthreads();                    // drains W writes too
    }
    {   // drain PV for last chunk (c=21, parity 1)
        short8 aw = ld8(&w16[wave][1][n][quad * 8]);
        o = MFMA16(aw, thp, o);
        o = MFMA16(aw, tlp, o);
    }
    if (jt < 98) {
        float* ob = opart + (size_t)ih * 802816 + ((size_t)b * 1568 + (size_t)jt * 16) * 16;
#pragma unroll
        for (int r = 0; r < 4; ++r) ob[(quad * 4 + r) * 16 + n] = o[r];
    }
}

// ---------------------------------------------------------------------------
// Final conv 7x7 (sums 3 opart parts) fused with LayerNorm epilogue.
__global__ __launch_bounds__(128) void k_conv7ln(const float* __restrict__ op0,
                                                 const float* __restrict__ op1,
                                                 const float* __restrict__ op2,
                                                 const float* __restrict__ w,
                                                 const float* __restrict__ gamma,
                                                 const float* __restrict__ beta,
                                                 float* __restrict__ out) {
    int bg = blockIdx.x;           // b*32+g
    int tid = threadIdx.x;
    __shared__ float patch[16 * 144];
    __shared__ float cvout[784];
    for (int t = tid; t < 16 * 144; t += 128) patch[t] = 0.f;
    __syncthreads();
    const float* p0 = op0 + (size_t)bg * 784;
    const float* p1 = op1 + (size_t)bg * 784;
    const float* p2 = op2 + (size_t)bg * 784;
    for (int t = tid; t < 784; t += 128) {
        int ic = t / 49, p = t % 49;
        int y = p / 7, x = p % 7;
        patch[ic * 144 + (y + 1) * 16 + (x + 1)] = p0[t] + p1[t] + p2[t];
    }
    __syncthreads();
    int g = bg & 31;
    int oh = tid >> 6, lt = tid & 63;
    const float* wg = w + (size_t)g * 2304 + (size_t)oh * 8 * 144;
    if (lt < 49) {
        int y = lt / 7, x = lt % 7;
        int base = (y + 1) * 16 + (x + 1);
        float acc[8];
#pragma unroll
        for (int oc = 0; oc < 8; ++oc) acc[oc] = 0.f;
        for (int ic = 0; ic < 16; ++ic) {
            const float* pr = patch + ic * 144 + base;
            float win[9];
#pragma unroll
            for (int ky = 0; ky < 3; ++ky)
#pragma unroll
                for (int kx = 0; kx < 3; ++kx)
                    win[ky * 3 + kx] = pr[(ky - 1) * 16 + (kx - 1)];
            const float* wi = wg + ic * 9;
#pragma unroll
            for (int oc = 0; oc < 8; ++oc)
#pragma unroll
                for (int kk = 0; kk < 9; ++kk)
                    acc[oc] += win[kk] * wi[oc * 144 + kk];
        }
#pragma unroll
        for (int oc = 0; oc < 8; ++oc) cvout[(oh * 8 + oc) * 49 + lt] = acc[oc];
    }
    __syncthreads();
    if (tid < 49) {                 // LN on 16 consecutive conv2-flat elements
        float v[16];
        float sum = 0.f;
#pragma unroll
        for (int k = 0; k < 16; ++k) { v[k] = cvout[tid * 16 + k]; sum += v[k]; }
        float mu = sum * 0.0625f;
        float var = 0.f;
#pragma unroll
        for (int k = 0; k < 16; ++k) { float d = v[k] - mu; var += d * d; }
        float rstd = rsqrtf(var * 0.0625f + 1e-5f);
        float4 o4[4];
#pragma unroll
        for (int k = 0; k < 16; ++k)
            ((float*)o4)[k] = (v[k] - mu) * rstd * gamma[k] + beta[k];
        float4* po = (float4*)(out + (size_t)bg * 784 + (size_t)tid * 16);
        po[0] = o4[0]; po[1] = o4[1]; po[2] = o4[2]; po[3] = o4[3];
    }
}

// ---------------------------------------------------------------------------
extern "C" void kernel_launch(void* const* d_in, const int* in_sizes, int n_in,
                              void* d_out, int out_size, void* d_ws, size_t ws_size,
                              hipStream_t stream) {
    const float* current_pose = (const float*)d_in[0];
    const float* next_pose    = (const float*)d_in[1];
    const float* current_w    = (const float*)d_in[2];
    const float* next_w       = (const float*)d_in[3];
    const float* E_proj       = (const float*)d_in[4];
    const float* rel          = (const float*)d_in[5];
    const float* ln_gamma     = (const float*)d_in[6];
    const float* ln_beta      = (const float*)d_in[7];
    float* out = (float*)d_out;
    float* ws  = (float*)d_ws;

    // workspace (floats); cpconv region reused by opart/dpart after kproj2
    float* cpconv = ws;                 // 3,211,264
    float* opart  = ws;                 // 3 x 802,816 -> ends 2,408,448
    float* dpart  = ws + 2408448;       // 2 x 67,584 -> ends 2,543,616
    float* w2     = ws + 3211264;       //    73,728 -> ends 3,284,992
    u16*   ub     = (u16*)(ws + 3284992);
    u16* Qp  = ub;                      // 1,605,632
    u16* Kh  = ub + 1605632;            // 1,081,344
    u16* Kl  = ub + 2686976;
    u16* KhT = ub + 3768320;
    u16* KlT = ub + 4849664;
    u16* EhT = ub + 5931008;            // 458,752
    u16* ElT = ub + 6389760;            // ends 6,848,512 (~26.8 MB total)

    k_ecvt2  <<<72,   256, 0, stream>>>(E_proj, rel, current_w, EhT, ElT,
                                        Kh, Kl, KhT, KlT, w2);
    k_conv14 <<<2048, 256, 0, stream>>>(current_pose, w2, cpconv);
    k_conv7q <<<1024, 128, 0, stream>>>(next_pose, next_w, Qp);
    k_kproj2 <<<1024, 256, 0, stream>>>(cpconv, EhT, ElT, Kh, Kl, KhT, KlT);
    k_stats4 <<<1088, 256, 0, stream>>>(Qp, Kh, Kl, dpart);
    k_kscale <<<128,  256, 0, stream>>>(dpart, KhT, KlT);
    k_pv6    <<<2400, 256, 0, stream>>>(Qp, Kh, Kl, KhT, KlT, opart);
    k_conv7ln<<<1024, 128, 0, stream>>>(opart, opart + 802816, opart + 1605632,
                                        next_w, ln_gamma, ln_beta, out);
    (void)in_sizes; (void)n_in; (void)out_size; (void)ws_size;
}